// Round 11
// baseline (301.414 us; speedup 1.0000x reference)
//
#include <hip/hip_runtime.h>
#include <hip/hip_cooperative_groups.h>
#include <math.h>

namespace cg = cooperative_groups;

constexpr int kB = 16;
constexpr int kN = 1024;
constexpr int kD = 128;
constexpr int kE = 16384;

typedef short bf16x8 __attribute__((ext_vector_type(8)));
typedef float f32x4 __attribute__((ext_vector_type(4)));
typedef unsigned short us4 __attribute__((ext_vector_type(4)));

__device__ __forceinline__ float selu_f(float x) {
    const float scale = 1.0507009873554805f;
    const float alpha = 1.6732632423543772f;
    return x > 0.f ? scale * x : scale * alpha * (expf(x) - 1.f);
}

__device__ __forceinline__ float sigmoid_f(float x) {
    return 1.f / (1.f + expf(-x));
}

__device__ __forceinline__ float bf2f(unsigned short u) {
    union { unsigned int i; float f; } x;
    x.i = ((unsigned int)u) << 16;
    return x.f;
}

// round-to-nearest-even f32 -> bf16
__device__ __forceinline__ unsigned short f2bf(float f) {
    union { float f; unsigned int i; } u;
    u.f = f;
    const unsigned int r = u.i + 0x7fffu + ((u.i >> 16) & 1u);
    return (unsigned short)(r >> 16);
}

struct MParams {
    const float* nodef; const float* edgef; const int* src; const int* tgt;
    const float* Wmsg; const float* bmsg; const float* Wih; const float* Whh;
    const float* bih; const float* bhh;
    const float* Wr1; const float* br1; const float* Wr2; const float* br2;
    const float* Wpol; const float* bpol;
    float* out;
    float* efg; float* bihP; float* bhhP; int* cnt; float* pooled;
    unsigned short* HST; unsigned short* hbfA; unsigned short* hbfB;
    unsigned short* agg; unsigned short* WcatT; unsigned short* Wfused;
    int* cursor; int* rowstart; int* sid; int* ssrc;
};

// ============ cooperative mega-kernel: 256 blocks x 256 threads ============
__launch_bounds__(256)
__global__ void k_mega(MParams P) {
    cg::grid_group grid = cg::this_grid();
    __shared__ __align__(16) unsigned char smemraw[65536];
    uint4* smem = (uint4*)smemraw;
    const int blk = blockIdx.x;  // 256
    const int t = threadIdx.x;   // 256

    // ---- A1: h_bf init (bf16) + zero cnt/pooled ----
    {
#pragma unroll
        for (int i = 0; i < 8; ++i) {
            const int base = blk * 8192 + i * 1024 + t * 4;
            const float4 v = *(const float4*)&P.nodef[base];
            us4 o;
            o.x = f2bf(v.x); o.y = f2bf(v.y); o.z = f2bf(v.z); o.w = f2bf(v.w);
            *(us4*)&P.hbfA[base] = o;
        }
        if (blk == 254) for (int i = t; i < 1024; i += 256) P.cnt[i] = 0;
        if (blk == 255) for (int i = t; i < 2048; i += 256) P.pooled[i] = 0.f;
    }
    grid.sync();
    // ---- A2: count tgt histogram ----
    if (blk < 64) atomicAdd(&P.cnt[P.tgt[blk * 256 + t]], 1);
    grid.sync();
    // ---- A3: scan (blk 0) + weight prep (blk 1..160) ----
    if (blk == 0) {
        int* wsum = (int*)smemraw;
        const int t4 = t * 4;
        const int v0 = P.cnt[t4], v1 = P.cnt[t4 + 1], v2 = P.cnt[t4 + 2], v3 = P.cnt[t4 + 3];
        wsum[t] = v0 + v1 + v2 + v3;
        __syncthreads();
        for (int off = 1; off < 256; off <<= 1) {
            const int add = (t >= off) ? wsum[t - off] : 0;
            __syncthreads();
            wsum[t] += add;
            __syncthreads();
        }
        int run = t ? wsum[t - 1] : 0;
        P.cursor[t4] = run; P.rowstart[t4] = run; run += v0;
        P.cursor[t4 + 1] = run; P.rowstart[t4 + 1] = run; run += v1;
        P.cursor[t4 + 2] = run; P.rowstart[t4 + 2] = run; run += v2;
        P.cursor[t4 + 3] = run; P.rowstart[t4 + 3] = run; run += v3;
        if (t == 255) P.rowstart[1024] = run;
    } else if (blk <= 160) {
#pragma unroll
        for (int jj = 0; jj < 2; ++jj) {
            const int j = (blk - 1) * 4 + jj * 2 + (t >> 7);  // 0..639
            const int k = t & 127;
            if (j < 256) {
                float v = (j < 128) ? P.Wmsg[k * 128 + j] : P.Wmsg[(128 + k) * 128 + (j - 128)];
                P.WcatT[j * 128 + k] = f2bf(v);
            } else {
                const int f = j - 256;  // col' in [0,384)
                const int dg = f / 48, rem = f % 48;
                const int g = rem / 16, di = rem % 16;
                const int orig = g * 128 + dg * 16 + di;
                P.Wfused[(size_t)f * 256 + k] = f2bf(P.Wih[(size_t)orig * 128 + k]);
                P.Wfused[(size_t)f * 256 + 128 + k] = f2bf(P.Whh[(size_t)orig * 128 + k]);
                if (k == 0) { P.bihP[f] = P.bih[orig]; P.bhhP[f] = P.bhh[orig]; }
            }
        }
    }
    grid.sync();
    // ---- A4: scatter (sorted-by-target edge list) ----
    if (blk < 64) {
        const int e = blk * 256 + t;
        const int tg = P.tgt[e];
        const int pos = atomicAdd(&P.cursor[tg], 1);
        P.sid[pos] = e;
        P.ssrc[pos] = P.src[e];
    }
    grid.sync();
    // ---- A5: gather ef in sorted order ----
#pragma unroll
    for (int i = 0; i < 4; ++i) {
        const int gid = blk * 1024 + i * 256 + t;
        const int b = gid >> 14, idx = gid & (kE - 1);
        const int eid = P.sid[idx];
        P.efg[gid] = P.edgef[((size_t)b << 20) + ((size_t)P.src[eid] << 10) + P.tgt[eid]];
    }
    grid.sync();

    // ---- main loop ----
    const int w = t >> 6, l = t & 63;
    const int lin = l & 15, kq = l >> 4, rq = kq * 4;
    for (int it = 0; it < 3; ++it) {
        const unsigned short* hcur = (it & 1) ? P.hbfB : P.hbfA;
        unsigned short* hnxt = (it & 1) ? P.hbfA : P.hbfB;

        // --- phase 1: HST[.][256] = h @ [W1|W2]  (1 tile/block) ---
        {
            uint4* As = smem;
            uint4* Bs = smem + 2048;
            const int r0 = (blk & 127) * 128;
            const int c0 = (blk >> 7) * 128;
            const uint4* gA = (const uint4*)(hcur + (size_t)r0 * 128);
            const uint4* gB = (const uint4*)(P.WcatT + (size_t)c0 * 128);
#pragma unroll
            for (int i = 0; i < 8; ++i) {
                const int f = i * 256 + t;
                const int row = f >> 4, c16 = f & 15;
                const int d = row * 16 + (c16 ^ (row & 7));
                As[d] = gA[f];
                Bs[d] = gB[f];
            }
            __syncthreads();
            const int wm = (w & 1) * 64, wn = (w >> 1) * 64;
            f32x4 acc[4][4] = {};
#pragma unroll
            for (int s = 0; s < 4; ++s) {
                bf16x8 a[4], b[4];
#pragma unroll
                for (int mi = 0; mi < 4; ++mi) {
                    const int row = wm + mi * 16 + lin;
                    a[mi] = *(const bf16x8*)&As[row * 16 + ((s * 4 + kq) ^ (row & 7))];
                }
#pragma unroll
                for (int ni = 0; ni < 4; ++ni) {
                    const int row = wn + ni * 16 + lin;
                    b[ni] = *(const bf16x8*)&Bs[row * 16 + ((s * 4 + kq) ^ (row & 7))];
                }
#pragma unroll
                for (int mi = 0; mi < 4; ++mi)
#pragma unroll
                    for (int ni = 0; ni < 4; ++ni)
                        acc[mi][ni] = __builtin_amdgcn_mfma_f32_16x16x32_bf16(
                            a[mi], b[ni], acc[mi][ni], 0, 0, 0);
            }
#pragma unroll
            for (int ni = 0; ni < 4; ++ni) {
                const int col = c0 + wn + ni * 16 + lin;
#pragma unroll
                for (int mi = 0; mi < 4; ++mi) {
                    const int row = r0 + wm + mi * 16 + rq;
#pragma unroll
                    for (int r = 0; r < 4; ++r)
                        P.HST[(size_t)(row + r) * 256 + col] = f2bf(acc[mi][ni][r]);
                }
            }
            __syncthreads();
        }
        grid.sync();

        // --- phase 2: per-target edge selu-reduce -> agg (32 units/block) ---
        {
            float4* part = (float4*)smemraw;  // ping-pong: 2 x [2][4][32]
            const int tl = t >> 7;
            const int slot = (t >> 5) & 3;
            const int lane = t & 31;
            const int c = lane * 4;
            const float4 w3 = *(const float4*)&P.Wmsg[256 * 128 + c];
            const float4 bm = *(const float4*)&P.bmsg[c];
#pragma unroll 1
            for (int u = 0; u < 32; ++u) {
                const int unit = blk * 32 + u;      // 0..8191
                const int b = unit >> 9;            // batch
                const int bx = unit & 511;
                const int tg = bx * 2 + tl;
                float4* pu = part + (u & 1) * 256;
                const size_t base = (size_t)b * kN;
                const us4 htu = *(const us4*)&P.HST[(base + tg) * 256 + 128 + c];
                const float hb0 = bf2f(htu.x) + bm.x;
                const float hb1 = bf2f(htu.y) + bm.y;
                const float hb2 = bf2f(htu.z) + bm.z;
                const float hb3 = bf2f(htu.w) + bm.w;
                const float* efb = P.efg + b * kE;
                const int j0 = P.rowstart[tg], j1 = P.rowstart[tg + 1];
                float a0 = 0.f, a1 = 0.f, a2 = 0.f, a3 = 0.f;
                for (int j = j0 + slot; j < j1; j += 4) {
                    const int s = P.ssrc[j];
                    const float ef = efb[j];
                    const us4 hs = *(const us4*)&P.HST[(base + s) * 256 + c];
                    a0 += selu_f(bf2f(hs.x) + fmaf(ef, w3.x, hb0));
                    a1 += selu_f(bf2f(hs.y) + fmaf(ef, w3.y, hb1));
                    a2 += selu_f(bf2f(hs.z) + fmaf(ef, w3.z, hb2));
                    a3 += selu_f(bf2f(hs.w) + fmaf(ef, w3.w, hb3));
                }
                pu[(tl * 4 + slot) * 32 + lane] = make_float4(a0, a1, a2, a3);
                __syncthreads();
                if (slot == 0) {
                    const float4 p1 = pu[(tl * 4 + 1) * 32 + lane];
                    const float4 p2 = pu[(tl * 4 + 2) * 32 + lane];
                    const float4 p3 = pu[(tl * 4 + 3) * 32 + lane];
                    a0 += p1.x + p2.x + p3.x;
                    a1 += p1.y + p2.y + p3.y;
                    a2 += p1.z + p2.z + p3.z;
                    a3 += p1.w + p2.w + p3.w;
                    us4 o;
                    o.x = f2bf(a0); o.y = f2bf(a1); o.z = f2bf(a2); o.w = f2bf(a3);
                    *(us4*)&P.agg[(base + tg) * 128 + c] = o;
                }
            }
            __syncthreads();
        }
        grid.sync();

        // --- phase 3: fused gi/gh GEMM + GRU (+pool last iter), 2 tiles/block ---
#pragma unroll 1
        for (int sub = 0; sub < 2; ++sub) {
            const int tile = blk + 256 * sub;  // 0..511
            uint4* As = smem;
            uint4* Bs = smem + 2048;
            const int r0 = (tile & 127) * 128;
            const int y = tile >> 7;  // [0,4)
            const int wm = (w & 1) * 64, wc0 = (w >> 1) * 48;
            f32x4 acc[4][3] = {};
            f32x4 accN[4] = {};
#pragma unroll
            for (int stage = 0; stage < 2; ++stage) {
                const unsigned short* Ap = stage ? hcur : P.agg;
                const uint4* gA = (const uint4*)(Ap + (size_t)r0 * 128);
#pragma unroll
                for (int i = 0; i < 8; ++i) {
                    const int f = i * 256 + t;
                    const int row = f >> 4, c16 = f & 15;
                    As[row * 16 + (c16 ^ (row & 7))] = gA[f];
                }
                const uint4* gW = (const uint4*)P.Wfused;
#pragma unroll
                for (int i = 0; i < 6; ++i) {
                    const int f = i * 256 + t;  // < 1536
                    const int j = f >> 4, c16 = f & 15;
                    Bs[j * 16 + (c16 ^ (j & 7))] = gW[(size_t)(y * 96 + j) * 32 + stage * 16 + c16];
                }
                __syncthreads();
#pragma unroll
                for (int ks = 0; ks < 4; ++ks) {
                    bf16x8 a[4], b[3];
#pragma unroll
                    for (int mi = 0; mi < 4; ++mi) {
                        const int row = wm + mi * 16 + lin;
                        a[mi] = *(const bf16x8*)&As[row * 16 + ((ks * 4 + kq) ^ (row & 7))];
                    }
#pragma unroll
                    for (int ni = 0; ni < 3; ++ni) {
                        const int row = wc0 + ni * 16 + lin;
                        b[ni] = *(const bf16x8*)&Bs[row * 16 + ((ks * 4 + kq) ^ (row & 7))];
                    }
#pragma unroll
                    for (int mi = 0; mi < 4; ++mi) {
                        acc[mi][0] = __builtin_amdgcn_mfma_f32_16x16x32_bf16(a[mi], b[0], acc[mi][0], 0, 0, 0);
                        acc[mi][1] = __builtin_amdgcn_mfma_f32_16x16x32_bf16(a[mi], b[1], acc[mi][1], 0, 0, 0);
                        if (stage == 0)
                            acc[mi][2] = __builtin_amdgcn_mfma_f32_16x16x32_bf16(a[mi], b[2], acc[mi][2], 0, 0, 0);
                        else
                            accN[mi] = __builtin_amdgcn_mfma_f32_16x16x32_bf16(a[mi], b[2], accN[mi], 0, 0, 0);
                    }
                }
                __syncthreads();
            }
            // GRU epilogue; hv from stage-1 LDS A-tile
            const int colR = y * 96 + wc0 + lin;
            const float bR = P.bihP[colR] + P.bhhP[colR];
            const float bZ = P.bihP[colR + 16] + P.bhhP[colR + 16];
            const float biN = P.bihP[colR + 32];
            const float bhN = P.bhhP[colR + 32];
            const int dgg = y * 2 + (wc0 / 48);
            const int d = dgg * 16 + lin;
            const int bb = r0 >> 10;
            const int dc = d >> 3, de = d & 7;
            float psum = 0.f;
#pragma unroll
            for (int mi = 0; mi < 4; ++mi) {
#pragma unroll
                for (int r = 0; r < 4; ++r) {
                    const int rowL = wm + mi * 16 + rq + r;
                    const float rr = sigmoid_f(acc[mi][0][r] + bR);
                    const float zz = sigmoid_f(acc[mi][1][r] + bZ);
                    const float i_n = acc[mi][2][r] + biN;
                    const float h_n = accN[mi][r] + bhN;
                    const float nn = tanhf(fmaf(rr, h_n, i_n));
                    const float hv = bf2f(((const unsigned short*)&As[rowL * 16 + (dc ^ (rowL & 7))])[de]);
                    const float o = fmaf(zz, hv - nn, nn);
                    hnxt[(size_t)(r0 + rowL) * 128 + d] = f2bf(o);
                    psum += o;
                }
            }
            if (it == 2) atomicAdd(&P.pooled[bb * 128 + d], psum);
            __syncthreads();
        }
        grid.sync();
    }

    // ---- head ----
    if (blk < 16) {
        float* p = (float*)smemraw;
        float* t1 = p + 128;
        const int b = blk;
        if (t < 128) p[t] = P.pooled[b * 128 + t];
        __syncthreads();
        if (t < 128) {
            float acc = P.br1[t];
            for (int k = 0; k < 128; ++k) acc = fmaf(p[k], P.Wr1[k * 128 + t], acc);
            t1[t] = selu_f(acc);
        }
        __syncthreads();
        float acc2 = 0.f;
        if (t < 128) {
            acc2 = P.br2[t];
            for (int k = 0; k < 128; ++k) acc2 = fmaf(t1[k], P.Wr2[k * 128 + t], acc2);
        }
        __syncthreads();
        if (t < 128) p[t] = selu_f(acc2);
        __syncthreads();
        if (t < 64) {
            float o = P.bpol[t];
            for (int k = 0; k < 128; ++k) o = fmaf(p[k], P.Wpol[k * 64 + t], o);
            P.out[b * 64 + t] = o;
        }
    }
}

// ============ fallback path: R9 multi-kernel (known-good) ============
__global__ void k_h0c(const float* __restrict__ nodef, unsigned short* __restrict__ h_bf,
                      const int* __restrict__ tgt, int* __restrict__ cnt) {
    int gid = blockIdx.x * 256 + threadIdx.x;
    h_bf[gid] = f2bf(nodef[gid]);
    if (gid < kE) atomicAdd(&cnt[tgt[gid]], 1);
}

__global__ void k_scan(const int* __restrict__ cnt, int* __restrict__ cursor,
                       int* __restrict__ rowstart) {
    __shared__ int s[kN];
    int t = threadIdx.x;
    int own = cnt[t];
    s[t] = own;
    __syncthreads();
    for (int off = 1; off < kN; off <<= 1) {
        int add = (t >= off) ? s[t - off] : 0;
        __syncthreads();
        s[t] += add;
        __syncthreads();
    }
    int excl = s[t] - own;
    cursor[t] = excl;
    rowstart[t] = excl;
    if (t == kN - 1) rowstart[kN] = s[t];
}

__global__ void k_scatter(const int* __restrict__ src, const int* __restrict__ tgt,
                          int* __restrict__ cursor, int* __restrict__ sid,
                          int* __restrict__ ssrc) {
    int e = blockIdx.x * 256 + threadIdx.x;
    int tg = tgt[e];
    int pos = atomicAdd(&cursor[tg], 1);
    sid[pos] = e;
    ssrc[pos] = src[e];
}

__global__ void k_gather_ef(const float* __restrict__ edgef, const int* __restrict__ src,
                            const int* __restrict__ tgt, const int* __restrict__ sid,
                            float* __restrict__ efg) {
    int gid = blockIdx.x * 256 + threadIdx.x;
    int b = gid >> 14;
    int i = gid & (kE - 1);
    int eid = sid[i];
    efg[gid] = edgef[(size_t)b * kN * kN + (size_t)src[eid] * kN + tgt[eid]];
}

__global__ void k_buildw(const float* __restrict__ Wmsg, const float* __restrict__ Whh,
                         const float* __restrict__ Wih,
                         const float* __restrict__ bih, const float* __restrict__ bhh,
                         unsigned short* __restrict__ WcatT,
                         unsigned short* __restrict__ Wfused,
                         float* __restrict__ bihP, float* __restrict__ bhhP) {
    const int j = blockIdx.x;
    const int k = threadIdx.x;
    if (j < 256) {
        float v = (j < 128) ? Wmsg[k * 128 + j] : Wmsg[(128 + k) * 128 + (j - 128)];
        WcatT[j * 128 + k] = f2bf(v);
    } else {
        const int f = j - 256;
        const int dg = f / 48, rem = f % 48;
        const int g = rem / 16, di = rem % 16;
        const int orig = g * 128 + dg * 16 + di;
        Wfused[(size_t)f * 256 + k] = f2bf(Wih[(size_t)orig * 128 + k]);
        Wfused[(size_t)f * 256 + 128 + k] = f2bf(Whh[(size_t)orig * 128 + k]);
        if (k == 0) { bihP[f] = bih[orig]; bhhP[f] = bhh[orig]; }
    }
}

__launch_bounds__(256)
__global__ void k_mm256(const unsigned short* __restrict__ A,
                        const unsigned short* __restrict__ Bt,
                        unsigned short* __restrict__ HST) {
    __shared__ uint4 As[2048];
    __shared__ uint4 Bs[2048];
    const int t = threadIdx.x;
    const int r0 = blockIdx.x * 128;
    const int c0 = blockIdx.y * 128;
    const uint4* gA = (const uint4*)(A + (size_t)r0 * 128);
    const uint4* gB = (const uint4*)(Bt + (size_t)c0 * 128);
#pragma unroll
    for (int i = 0; i < 8; ++i) {
        const int f = i * 256 + t;
        const int row = f >> 4, c16 = f & 15;
        const int d = row * 16 + (c16 ^ (row & 7));
        As[d] = gA[f];
        Bs[d] = gB[f];
    }
    __syncthreads();
    const int w = t >> 6, l = t & 63;
    const int wm = (w & 1) * 64, wn = (w >> 1) * 64;
    const int lin = l & 15, kq = l >> 4;
    f32x4 acc[4][4] = {};
#pragma unroll
    for (int s = 0; s < 4; ++s) {
        bf16x8 a[4], b[4];
#pragma unroll
        for (int mi = 0; mi < 4; ++mi) {
            const int row = wm + mi * 16 + lin;
            a[mi] = *(const bf16x8*)&As[row * 16 + ((s * 4 + kq) ^ (row & 7))];
        }
#pragma unroll
        for (int ni = 0; ni < 4; ++ni) {
            const int row = wn + ni * 16 + lin;
            b[ni] = *(const bf16x8*)&Bs[row * 16 + ((s * 4 + kq) ^ (row & 7))];
        }
#pragma unroll
        for (int mi = 0; mi < 4; ++mi)
#pragma unroll
            for (int ni = 0; ni < 4; ++ni)
                acc[mi][ni] = __builtin_amdgcn_mfma_f32_16x16x32_bf16(
                    a[mi], b[ni], acc[mi][ni], 0, 0, 0);
    }
    const int rq = kq * 4;
#pragma unroll
    for (int ni = 0; ni < 4; ++ni) {
        const int col = c0 + wn + ni * 16 + lin;
#pragma unroll
        for (int mi = 0; mi < 4; ++mi) {
            const int row = r0 + wm + mi * 16 + rq;
#pragma unroll
            for (int r = 0; r < 4; ++r)
                HST[(size_t)(row + r) * 256 + col] = f2bf(acc[mi][ni][r]);
        }
    }
}

__launch_bounds__(256)
__global__ void k_edge(const unsigned short* __restrict__ HST, const float* __restrict__ efg,
                       const int* __restrict__ ssrc, const int* __restrict__ rowstart,
                       const float* __restrict__ Wmsg, const float* __restrict__ bmsg,
                       unsigned short* __restrict__ agg_bf) {
    __shared__ float4 part[2][4][32];
    const int t = threadIdx.x;
    const int b = blockIdx.y;
    const int tl = t >> 7;
    const int tg = blockIdx.x * 2 + tl;
    const int slot = (t >> 5) & 3;
    const int lane = t & 31;
    const int c = lane * 4;
    const float4 w3 = *(const float4*)&Wmsg[256 * 128 + c];
    const float4 bm = *(const float4*)&bmsg[c];
    const size_t base = (size_t)b * kN;
    const us4 htu = *(const us4*)&HST[(base + tg) * 256 + 128 + c];
    const float hb0 = bf2f(htu.x) + bm.x;
    const float hb1 = bf2f(htu.y) + bm.y;
    const float hb2 = bf2f(htu.z) + bm.z;
    const float hb3 = bf2f(htu.w) + bm.w;
    const float* efb = efg + b * kE;
    const int j0 = rowstart[tg], j1 = rowstart[tg + 1];
    float a0 = 0.f, a1 = 0.f, a2 = 0.f, a3 = 0.f;
    for (int j = j0 + slot; j < j1; j += 4) {
        const int s = ssrc[j];
        const float ef = efb[j];
        const us4 hs = *(const us4*)&HST[(base + s) * 256 + c];
        a0 += selu_f(bf2f(hs.x) + fmaf(ef, w3.x, hb0));
        a1 += selu_f(bf2f(hs.y) + fmaf(ef, w3.y, hb1));
        a2 += selu_f(bf2f(hs.z) + fmaf(ef, w3.z, hb2));
        a3 += selu_f(bf2f(hs.w) + fmaf(ef, w3.w, hb3));
    }
    part[tl][slot][lane] = make_float4(a0, a1, a2, a3);
    __syncthreads();
    if (slot == 0) {
        const float4 p1 = part[tl][1][lane];
        const float4 p2 = part[tl][2][lane];
        const float4 p3 = part[tl][3][lane];
        a0 += p1.x + p2.x + p3.x;
        a1 += p1.y + p2.y + p3.y;
        a2 += p1.z + p2.z + p3.z;
        a3 += p1.w + p2.w + p3.w;
        us4 o;
        o.x = f2bf(a0); o.y = f2bf(a1); o.z = f2bf(a2); o.w = f2bf(a3);
        *(us4*)&agg_bf[(base + tg) * 128 + c] = o;
    }
}

__launch_bounds__(256)
__global__ void k_gigru(const unsigned short* __restrict__ agg_bf,
                        const unsigned short* __restrict__ h_bf_in,
                        const unsigned short* __restrict__ Wfused,
                        const float* __restrict__ bihP, const float* __restrict__ bhhP,
                        unsigned short* __restrict__ h_bf_out,
                        float* __restrict__ pooled, int lastIter) {
    __shared__ uint4 As[2048];
    __shared__ uint4 Bs[1536];
    const int t = threadIdx.x;
    const int r0 = blockIdx.x * 128;
    const int y = blockIdx.y;
    const int w = t >> 6, l = t & 63;
    const int wm = (w & 1) * 64, wc0 = (w >> 1) * 48;
    const int lin = l & 15, kq = l >> 4, rq = kq * 4;
    f32x4 acc[4][3] = {};
    f32x4 accN[4] = {};
#pragma unroll
    for (int stage = 0; stage < 2; ++stage) {
        const unsigned short* Ap = stage ? h_bf_in : agg_bf;
        const uint4* gA = (const uint4*)(Ap + (size_t)r0 * 128);
#pragma unroll
        for (int i = 0; i < 8; ++i) {
            const int f = i * 256 + t;
            const int row = f >> 4, c16 = f & 15;
            As[row * 16 + (c16 ^ (row & 7))] = gA[f];
        }
        const uint4* gW = (const uint4*)Wfused;
#pragma unroll
        for (int i = 0; i < 6; ++i) {
            const int f = i * 256 + t;
            const int j = f >> 4, c16 = f & 15;
            Bs[j * 16 + (c16 ^ (j & 7))] = gW[(size_t)(y * 96 + j) * 32 + stage * 16 + c16];
        }
        __syncthreads();
#pragma unroll
        for (int ks = 0; ks < 4; ++ks) {
            bf16x8 a[4], b[3];
#pragma unroll
            for (int mi = 0; mi < 4; ++mi) {
                const int row = wm + mi * 16 + lin;
                a[mi] = *(const bf16x8*)&As[row * 16 + ((ks * 4 + kq) ^ (row & 7))];
            }
#pragma unroll
            for (int ni = 0; ni < 3; ++ni) {
                const int row = wc0 + ni * 16 + lin;
                b[ni] = *(const bf16x8*)&Bs[row * 16 + ((ks * 4 + kq) ^ (row & 7))];
            }
#pragma unroll
            for (int mi = 0; mi < 4; ++mi) {
                acc[mi][0] = __builtin_amdgcn_mfma_f32_16x16x32_bf16(a[mi], b[0], acc[mi][0], 0, 0, 0);
                acc[mi][1] = __builtin_amdgcn_mfma_f32_16x16x32_bf16(a[mi], b[1], acc[mi][1], 0, 0, 0);
                if (stage == 0)
                    acc[mi][2] = __builtin_amdgcn_mfma_f32_16x16x32_bf16(a[mi], b[2], acc[mi][2], 0, 0, 0);
                else
                    accN[mi] = __builtin_amdgcn_mfma_f32_16x16x32_bf16(a[mi], b[2], accN[mi], 0, 0, 0);
            }
        }
        __syncthreads();
    }
    const int colR = y * 96 + wc0 + lin;
    const float bR = bihP[colR] + bhhP[colR];
    const float bZ = bihP[colR + 16] + bhhP[colR + 16];
    const float biN = bihP[colR + 32];
    const float bhN = bhhP[colR + 32];
    const int dgg = y * 2 + (wc0 / 48);
    const int d = dgg * 16 + lin;
    const int bb = r0 >> 10;
    const int dc = d >> 3, de = d & 7;
    float psum = 0.f;
#pragma unroll
    for (int mi = 0; mi < 4; ++mi) {
#pragma unroll
        for (int r = 0; r < 4; ++r) {
            const int rowL = wm + mi * 16 + rq + r;
            const float rr = sigmoid_f(acc[mi][0][r] + bR);
            const float zz = sigmoid_f(acc[mi][1][r] + bZ);
            const float i_n = acc[mi][2][r] + biN;
            const float h_n = accN[mi][r] + bhN;
            const float nn = tanhf(fmaf(rr, h_n, i_n));
            const float hv = bf2f(((const unsigned short*)&As[rowL * 16 + (dc ^ (rowL & 7))])[de]);
            const float o = fmaf(zz, hv - nn, nn);
            h_bf_out[(size_t)(r0 + rowL) * 128 + d] = f2bf(o);
            psum += o;
        }
    }
    if (lastIter) atomicAdd(&pooled[bb * 128 + d], psum);
}

__global__ void k_head(const float* __restrict__ pooled,
                       const float* __restrict__ Wr1, const float* __restrict__ br1,
                       const float* __restrict__ Wr2, const float* __restrict__ br2,
                       const float* __restrict__ Wpol, const float* __restrict__ bpol,
                       float* __restrict__ out) {
    __shared__ float p[128], t1[128];
    const int b = blockIdx.x, d = threadIdx.x;
    p[d] = pooled[b * 128 + d];
    __syncthreads();
    float acc = br1[d];
    for (int k = 0; k < 128; ++k) acc = fmaf(p[k], Wr1[k * 128 + d], acc);
    t1[d] = selu_f(acc);
    __syncthreads();
    acc = br2[d];
    for (int k = 0; k < 128; ++k) acc = fmaf(t1[k], Wr2[k * 128 + d], acc);
    __syncthreads();
    p[d] = selu_f(acc);
    __syncthreads();
    if (d < 64) {
        float o = bpol[d];
        for (int k = 0; k < 128; ++k) o = fmaf(p[k], Wpol[k * 64 + d], o);
        out[b * 64 + d] = o;
    }
}

extern "C" void kernel_launch(void* const* d_in, const int* in_sizes, int n_in,
                              void* d_out, int out_size, void* d_ws, size_t ws_size,
                              hipStream_t stream) {
    MParams P;
    P.nodef = (const float*)d_in[0];
    P.edgef = (const float*)d_in[1];
    P.src = (const int*)d_in[2];
    P.tgt = (const int*)d_in[3];
    P.Wmsg = (const float*)d_in[4];
    P.bmsg = (const float*)d_in[5];
    P.Wih = (const float*)d_in[6];
    P.Whh = (const float*)d_in[7];
    P.bih = (const float*)d_in[8];
    P.bhh = (const float*)d_in[9];
    P.Wr1 = (const float*)d_in[10];
    P.br1 = (const float*)d_in[11];
    P.Wr2 = (const float*)d_in[12];
    P.br2 = (const float*)d_in[13];
    P.Wpol = (const float*)d_in[14];
    P.bpol = (const float*)d_in[15];
    P.out = (float*)d_out;

    float* ws = (float*)d_ws;
    P.efg = ws;                                         // 262,144 f
    P.bihP = P.efg + 262144;                            // 384 f
    P.bhhP = P.bihP + 384;                              // 384 f
    P.cnt = (int*)(P.bhhP + 384);                       // 1,024 i
    P.pooled = (float*)(P.cnt + 1024);                  // 2,048 f
    P.HST = (unsigned short*)(P.pooled + 2048);         // 4,194,304 e
    P.hbfA = P.HST + 4194304;                           // 2,097,152 e
    P.hbfB = P.hbfA + 2097152;                          // 2,097,152 e
    P.agg = P.hbfB + 2097152;                           // 2,097,152 e
    P.WcatT = P.agg + 2097152;                          // 32,768 e
    P.Wfused = P.WcatT + 32768;                         // 98,304 e
    P.cursor = (int*)(P.Wfused + 98304);                // 1,024
    P.rowstart = P.cursor + 1024;                       // 1,040 (1025 used)
    P.sid = P.rowstart + 1040;                          // 16,384
    P.ssrc = P.sid + 16384;                             // 16,384

    // Gate: cooperative only if supported AND 256 blocks provably co-resident.
    int dev = 0;
    hipGetDevice(&dev);
    int coop = 0;
    hipDeviceGetAttribute(&coop, hipDeviceAttributeCooperativeLaunch, dev);
    int numCU = 0;
    hipDeviceGetAttribute(&numCU, hipDeviceAttributeMultiprocessorCount, dev);
    int maxBlk = 0;
    hipOccupancyMaxActiveBlocksPerMultiprocessor(&maxBlk, k_mega, 256, 0);
    const bool useCoop = coop && (maxBlk > 0) && ((long)maxBlk * numCU >= 256);

    if (useCoop) {
        void* args[] = {&P};
        hipLaunchCooperativeKernel(k_mega, dim3(256), dim3(256), args, 0u, stream);
        return;
    }

    // ---- fallback: R9 multi-kernel path ----
    hipMemsetAsync(P.cnt, 0, (1024 + 2048) * sizeof(int), stream);
    k_h0c<<<(kB * kN * kD) / 256, 256, 0, stream>>>(P.nodef, P.hbfA, P.tgt, P.cnt);
    k_scan<<<1, 1024, 0, stream>>>(P.cnt, P.cursor, P.rowstart);
    k_scatter<<<kE / 256, 256, 0, stream>>>(P.src, P.tgt, P.cursor, P.sid, P.ssrc);
    k_gather_ef<<<(kB * kE) / 256, 256, 0, stream>>>(P.edgef, P.src, P.tgt, P.sid, P.efg);
    k_buildw<<<640, 128, 0, stream>>>(P.Wmsg, P.Whh, P.Wih, P.bih, P.bhh, P.WcatT, P.Wfused,
                                      P.bihP, P.bhhP);
    for (int it = 0; it < 3; ++it) {
        unsigned short* hcur = (it & 1) ? P.hbfB : P.hbfA;
        unsigned short* hnxt = (it & 1) ? P.hbfA : P.hbfB;
        k_mm256<<<dim3(128, 2), 256, 0, stream>>>(hcur, P.WcatT, P.HST);
        k_edge<<<dim3(kN / 2, kB), 256, 0, stream>>>(P.HST, P.efg, P.ssrc, P.rowstart,
                                                     P.Wmsg, P.bmsg, P.agg);
        k_gigru<<<dim3(128, 4), 256, 0, stream>>>(P.agg, hcur, P.Wfused, P.bihP, P.bhhP, hnxt,
                                                  P.pooled, it == 2 ? 1 : 0);
    }
    k_head<<<kB, 128, 0, stream>>>(P.pooled, P.Wr1, P.br1, P.Wr2, P.br2, P.Wpol, P.bpol, P.out);
}